// Round 11
// baseline (1034.475 us; speedup 1.0000x reference)
//
#include <hip/hip_runtime.h>
#include <math.h>

#define N_NODES 40000
#define MP      40192   // 157 * 256
#define NROWB   157
#define N_EDGES 640000
#define N_GRAPHS 64
#define F_IN 32
#define D_EMB 256
#define D_HID 512
#define D_FC 1024
#define N_CLS 10

typedef _Float16 f16x8 __attribute__((ext_vector_type(8)));
typedef float f32x4  __attribute__((ext_vector_type(4)));
typedef unsigned short u16;

template <int N> struct VecU;
template <> struct VecU<2> { typedef unsigned T __attribute__((ext_vector_type(2))); };
template <> struct VecU<4> { typedef unsigned T __attribute__((ext_vector_type(4))); };

__device__ __forceinline__ float h2f(u16 u) {
    union { u16 s; _Float16 h; } v; v.s = u; return (float)v.h;
}
__device__ __forceinline__ u16 f2h(float f) {
    union { u16 s; _Float16 h; } v; v.h = (_Float16)f; return v.s;
}
// R20: one-instruction f16xf32+f32 FMA pair (lo/hi of a packed u32) —
// bit-identical to cvt+fmac at half the VALU issue count.
__device__ __forceinline__ void fma_mix2(float& a0, float& a1, unsigned u, float v) {
    asm("v_fma_mix_f32 %0, %2, %3, %0 op_sel:[0,0,0] op_sel_hi:[1,0,0]\n\t"
        "v_fma_mix_f32 %1, %2, %3, %1 op_sel:[1,0,0] op_sel_hi:[1,0,0]"
        : "+v"(a0), "+v"(a1) : "v"(u), "v"(v));
}

// ---------------------------------------------------------------------------
// Packed operand layout (R16): A as 256-row x 32-k 16KB chunks (XOR-swizzled
// image); W as 128-row x 32-k 8KB tiles. pk_idx = u16 offset of (row, quad).
// R23: NO LDS W-staging — both A and W fragments stream global->VGPR as
// contiguous 1KB wave-loads, register-double-buffered (6 loads in flight in
// distinct named regs; R22's pair-depth was flattened by the compiler,
// VGPR stuck at 52 -> the in-flight window was never actually widened).
// W is L2-resident (512KB/XCD, re-read per wave — 41MB/XCD per GEMM, far
// under the per-XCD L2 ceiling). K-loop: zero barriers, zero LDS.
// ---------------------------------------------------------------------------
__device__ __forceinline__ int pk_idx(int r, int q) {
    int rp = r >> 1;
    int g  = (((r & 1) << 2) | q) ^ (rp & 7);
    return rp * 64 + g * 8;
}

__global__ void prep_all(const float* __restrict__ x, u16* __restrict__ xb, u16* __restrict__ G,
                         float* __restrict__ deg, int* __restrict__ cnt, int* __restrict__ cursor,
                         float* __restrict__ sums) {
    int i = blockIdx.x * blockDim.x + threadIdx.x;
    if (i < N_NODES) { deg[i] = 1.0f; cnt[i] = 0; cursor[i] = 0; }
    if (i < MP * F_IN) {
        int row = i >> 5, colk = i & 31;
        float v = (row < N_NODES) ? x[i] : 0.f;
        size_t idx = (size_t)(row >> 8) * 8192 + pk_idx(row & 255, colk >> 3) + (colk & 7);
        xb[idx] = f2h(v);
    }
    if (i < 16 * 3072) {                     // 512-packed pad rows (rowblk 156, rows 160..255)
        int kc = i / 3072, rem = i % 3072;
        G[(size_t)(156 * 16 + kc) * 8192 + 5120 + rem] = 0;
    } else if (i < 16 * 3072 + 8 * 3072) {   // 256-packed pad rows
        int j = i - 16 * 3072;
        int kc = j / 3072, rem = j % 3072;
        G[(size_t)(156 * 8 + kc) * 8192 + 5120 + rem] = 0;
    }
    if (i < N_GRAPHS * D_HID) sums[i] = 0.f;
}

__global__ void edge_mlp_deg(const float* __restrict__ edge_attr,
                             const float* __restrict__ ep_w1, const float* __restrict__ ep_b1,
                             const float* __restrict__ ep_w2, const float* __restrict__ ep_b2,
                             const int* __restrict__ dst,
                             float* __restrict__ ew, float* __restrict__ deg, int* __restrict__ cnt) {
    __shared__ float w1[64], b1[64], w2[64];
    int t = threadIdx.x;
    if (t < 64) { w1[t] = ep_w1[t]; b1[t] = ep_b1[t]; w2[t] = ep_w2[t]; }
    __syncthreads();
    int e = blockIdx.x * blockDim.x + t;
    if (e >= N_EDGES) return;
    float x = edge_attr[e];
    float s = ep_b2[0];
#pragma unroll
    for (int j = 0; j < 64; ++j) s += fmaxf(x * w1[j] + b1[j], 0.f) * w2[j];
    float sig = 1.f / (1.f + expf(-s));
    ew[e] = sig;
    int d = dst[e];
    atomicAdd(&deg[d], sig);
    atomicAdd(&cnt[d], 1);
}

__global__ void dinv_kernel(const float* __restrict__ deg, float* __restrict__ dinv,
                            float* __restrict__ nloop) {
    int i = blockIdx.x * blockDim.x + threadIdx.x;
    if (i >= N_NODES) return;
    float d = deg[i];
    float r = (d > 0.f) ? rsqrtf(fmaxf(d, 1e-12f)) : 0.f;
    dinv[i] = r;
    nloop[i] = r * r;
}

__global__ void scan_kernel(const int* __restrict__ cnt, int* __restrict__ rowptr) {
    __shared__ int part[1024];
    int t = threadIdx.x;
    const int PER = (N_NODES + 1023) / 1024;
    int base = t * PER;
    int s = 0;
    for (int k = 0; k < PER; ++k) { int i = base + k; if (i < N_NODES) s += cnt[i]; }
    part[t] = s;
    __syncthreads();
    for (int off = 1; off < 1024; off <<= 1) {
        int v = (t >= off) ? part[t - off] : 0;
        __syncthreads();
        part[t] += v;
        __syncthreads();
    }
    int run = (t == 0) ? 0 : part[t - 1];
    for (int k = 0; k < PER; ++k) {
        int i = base + k;
        if (i < N_NODES) { rowptr[i] = run; run += cnt[i]; }
    }
    if (t == 1023) rowptr[N_NODES] = run;
}

__global__ void fill_csr_kernel(const int* __restrict__ src, const int* __restrict__ dst,
                                const float* __restrict__ ew, const float* __restrict__ dinv,
                                const int* __restrict__ rowptr, int* __restrict__ cursor,
                                int2* __restrict__ cv) {
    int e = blockIdx.x * blockDim.x + threadIdx.x;
    if (e >= N_EDGES) return;
    int d = dst[e];
    int s = src[e];
    float n = dinv[s] * ew[e] * dinv[d];
    int p = rowptr[d] + atomicAdd(&cursor[d], 1);
    cv[p] = make_int2(s, __float_as_int(n));
}

// ---------------------------------------------------------------------------
struct WPair { const float* s; u16* d; int K; int N; };
struct WP8 { WPair m[8]; };

__global__ void wprep_all(WP8 a) {
    __shared__ u16 th[32][33];
    WPair w = a.m[blockIdx.z];
    int n0 = blockIdx.x * 32;
    int k0 = blockIdx.y * 32;
    if (n0 >= w.N || k0 >= w.K) return;
    int tx = threadIdx.x, ty = threadIdx.y;
#pragma unroll
    for (int r = 0; r < 4; ++r) {
        int k = ty + r * 8;
        th[k][tx] = f2h(w.s[(size_t)(k0 + k) * w.N + n0 + tx]);
    }
    __syncthreads();
#pragma unroll
    for (int r = 0; r < 4; ++r) {
        int n = ty + r * 8;
        int R = n0 + n;
        int kcol = k0 + tx;
        size_t idx = ((size_t)(R >> 7) * (w.K >> 5) + (kcol >> 5)) * 4096
                   + pk_idx(R & 127, (kcol >> 3) & 3) + (kcol & 7);
        w.d[idx] = th[tx][n];
    }
}

// ---------------------------------------------------------------------------
// R23 GEMM: BM=256 x BN=64, 512 threads (8 waves, one 32-row strip each).
// NO K-loop LDS: A (2x1KB) and W (4x1KB) fragments stream straight from
// packed global into VGPRs each K-step, register-double-buffered — 6 loads
// in flight per wave in distinct named registers. Zero barriers in K-loop.
// Epilogue: single-pass eb (37KB LDS), one barrier. C / Cpk / pool paths.
// ---------------------------------------------------------------------------
__launch_bounds__(512)
__global__ void mfma_gemm(const u16* __restrict__ A,
                          const u16* __restrict__ W,
                          const float* __restrict__ bias,
                          const u16* __restrict__ skip,
                          u16* __restrict__ C, u16* __restrict__ Cpk,
                          int K, int N,
                          const int* __restrict__ batch, float* __restrict__ pool) {
    __shared__ __align__(16) u16 eb[256 * 72];   // 36.9 KB epilogue buffer
    __shared__ int sbatch[256];

    const int nColB = N >> 6;
    int b = blockIdx.x;
    int rowI = (b >> 3) / nColB * 8 + (b & 7);
    int colI = (b >> 3) % nColB;
    if (rowI >= NROWB) return;
    int rowBase = rowI * 256;
    int colBase = colI * 64;

    int t = threadIdx.x;
    int lane = t & 63;
    int wave = t >> 6;          // owns rows wave*32 .. +32
    int quad = lane >> 4;
    int mrow = lane & 15;
    int nIter = K >> 5;

    // per-lane swizzled granule offset (identical for A and W packed reads)
    int sw = (((mrow & 1) << 2) | quad) ^ ((mrow >> 1) & 7);
    int laneA = (wave * 16 + (mrow >> 1)) * 64 + sw * 8;   // wave's 32-row strip
    int laneW = (mrow >> 1) * 64 + sw * 8;                 // col-tile j adds j*512

    const u16* pA = A + (size_t)rowI * nIter * 8192;
    const u16* pW = W + ((size_t)(colI >> 1) * nIter) * 4096 + (colI & 1) * 2048;

    // current fragments (step 0)
    f16x8 a0 = *(const f16x8*)&pA[laneA];
    f16x8 a1 = *(const f16x8*)&pA[laneA + 512];
    f16x8 w0 = *(const f16x8*)&pW[laneW];
    f16x8 w1 = *(const f16x8*)&pW[laneW + 512];
    f16x8 w2 = *(const f16x8*)&pW[laneW + 1024];
    f16x8 w3 = *(const f16x8*)&pW[laneW + 1536];
    f16x8 na0, na1, nw0, nw1, nw2, nw3;

    f32x4 acc[2][4] = {};

    for (int it = 0; it < nIter; ++it) {
        if (it + 1 < nIter) {                       // prefetch step it+1 (6x1KB in flight)
            const u16* nA = pA + (size_t)(it + 1) * 8192;
            const u16* nW = pW + (size_t)(it + 1) * 4096;
            na0 = *(const f16x8*)&nA[laneA];
            na1 = *(const f16x8*)&nA[laneA + 512];
            nw0 = *(const f16x8*)&nW[laneW];
            nw1 = *(const f16x8*)&nW[laneW + 512];
            nw2 = *(const f16x8*)&nW[laneW + 1024];
            nw3 = *(const f16x8*)&nW[laneW + 1536];
        }
        __builtin_amdgcn_sched_barrier(0);          // keep prefetch above MFMA
        acc[0][0] = __builtin_amdgcn_mfma_f32_16x16x32_f16(a0, w0, acc[0][0], 0, 0, 0);
        acc[1][0] = __builtin_amdgcn_mfma_f32_16x16x32_f16(a1, w0, acc[1][0], 0, 0, 0);
        acc[0][1] = __builtin_amdgcn_mfma_f32_16x16x32_f16(a0, w1, acc[0][1], 0, 0, 0);
        acc[1][1] = __builtin_amdgcn_mfma_f32_16x16x32_f16(a1, w1, acc[1][1], 0, 0, 0);
        acc[0][2] = __builtin_amdgcn_mfma_f32_16x16x32_f16(a0, w2, acc[0][2], 0, 0, 0);
        acc[1][2] = __builtin_amdgcn_mfma_f32_16x16x32_f16(a1, w2, acc[1][2], 0, 0, 0);
        acc[0][3] = __builtin_amdgcn_mfma_f32_16x16x32_f16(a0, w3, acc[0][3], 0, 0, 0);
        acc[1][3] = __builtin_amdgcn_mfma_f32_16x16x32_f16(a1, w3, acc[1][3], 0, 0, 0);
        a0 = na0; a1 = na1; w0 = nw0; w1 = nw1; w2 = nw2; w3 = nw3;
    }

    // ---- single-pass epilogue ----
    const int ES = 72;                              // 144B rows, 16B-aligned
#pragma unroll
    for (int j = 0; j < 4; ++j) {
        int col = colBase + j * 16 + mrow;
        float bv = bias[col];
#pragma unroll
        for (int i = 0; i < 2; ++i) {
#pragma unroll
            for (int r = 0; r < 4; ++r) {
                int lr = (wave >> 2) * 128 + (wave & 3) * 32 + i * 16 + quad * 4 + r;
                size_t row = (size_t)rowBase + lr;
                float v = fmaxf(acc[i][j][r] + bv, 0.f);
                if (skip) v += h2f(skip[row * N + col]);
                eb[lr * ES + j * 16 + mrow] = f2h(v);
            }
        }
    }
    if (pool && t < 256) {
        int row = rowBase + t;
        sbatch[t] = (row < N_NODES) ? batch[row] : -1;
    }
    __syncthreads();
    if (C) {
#pragma unroll
        for (int k2 = 0; k2 < 4; ++k2) {
            int c = t + k2 * 512;
            int row = c >> 3, ch = c & 7;
            f16x8 v = *(const f16x8*)&eb[row * ES + ch * 8];
            *(f16x8*)&C[(size_t)(rowBase + row) * N + colBase + ch * 8] = v;
        }
    } else if (Cpk) {
#pragma unroll
        for (int k2 = 0; k2 < 4; ++k2) {
            int c = t + k2 * 512;
            int row = c >> 3, ch = c & 7;
            f16x8 v = *(const f16x8*)&eb[row * ES + ch * 8];
            size_t idx = ((size_t)rowI * (N >> 5) + (colBase >> 5) + (ch >> 2)) * 8192
                       + pk_idx(row, ch & 3);
            *(f16x8*)&Cpk[idx] = v;
        }
    }
    if (pool) {
        int c = t & 63;
        int rs = (t >> 6) * 32;
        float run = 0.f; int g = -1;
        for (int r = rs; r < rs + 32; ++r) {
            int bg = sbatch[r];
            if (bg != g) {
                if (g >= 0) atomicAdd(&pool[(size_t)g * D_HID + colBase + c], run);
                run = 0.f; g = bg;
            }
            if (bg >= 0) run += h2f(eb[r * ES + c]);
        }
        if (g >= 0) atomicAdd(&pool[(size_t)g * D_HID + colBase + c], run);
    }
}

// ---------------------------------------------------------------------------
// R19 gather: XCD column-sliced; R20: fma_mix accumulate. Output packed.
// ---------------------------------------------------------------------------
template <int D>
__launch_bounds__(256)
__global__ void gather_f16(const u16* __restrict__ h, const int* __restrict__ rowptr,
                           const int2* __restrict__ cv, const float* __restrict__ nloop,
                           u16* __restrict__ out) {
    constexpr int COLS = D / 8;       // cols per XCD slice (64 / 32)
    constexpr int LPG  = COLS / 8;    // lanes per node sub-group (8 / 4)
    constexpr int NPB  = 256 / LPG;   // nodes per block (32 / 64)
    using VU = typename VecU<4>::T;   // 16B = 8 f16
    int b = blockIdx.x;
    int slice = b & 7;
    int ng = b >> 3;
    int t = threadIdx.x;
    int node = ng * NPB + t / LPG;
    int l = t % LPG;
    if (node >= N_NODES) return;
    const u16* hs = h + slice * COLS + l * 8;   // per-lane 8-col window
    float acc[8];
    float sl = nloop[node];
    {
        VU own = *(const VU*)(hs + (size_t)node * D);
#pragma unroll
        for (int u = 0; u < 4; ++u) {
            acc[2 * u] = 0.f; acc[2 * u + 1] = 0.f;
            fma_mix2(acc[2 * u], acc[2 * u + 1], own[u], sl);
        }
    }
    int beg = rowptr[node], end = rowptr[node + 1];
    if (end > beg) {
        int last = end - 1;
        int2 c[8];
#pragma unroll
        for (int m = 0; m < 8; ++m) c[m] = cv[min(beg + m, last)];
        for (int j = beg; j < end; j += 8) {
            VU tv[8];
#pragma unroll
            for (int m = 0; m < 8; ++m)
                tv[m] = *(const VU*)(hs + (size_t)c[m].x * D);
            int jn = j + 8;
            int2 cn[8];
#pragma unroll
            for (int m = 0; m < 8; ++m) cn[m] = c[m];
            if (jn < end) {
#pragma unroll
                for (int m = 0; m < 8; ++m) cn[m] = cv[min(jn + m, last)];
            }
            __builtin_amdgcn_sched_barrier(0);
#pragma unroll
            for (int m = 0; m < 8; ++m) {
                float v = (j + m < end) ? __int_as_float(c[m].y) : 0.f;
#pragma unroll
                for (int u = 0; u < 4; ++u)
                    fma_mix2(acc[2 * u], acc[2 * u + 1], tv[m][u], v);
            }
#pragma unroll
            for (int m = 0; m < 8; ++m) c[m] = cn[m];
        }
    }
    VU o;
#pragma unroll
    for (int u = 0; u < 4; ++u) {
        unsigned lo = f2h(acc[2 * u]);
        unsigned hi = f2h(acc[2 * u + 1]);
        o[u] = lo | (hi << 16);
    }
    size_t blkb = (size_t)(node >> 8) * (D >> 5);
    int rr = node & 255;
    int kc, q;
    if (D == 512) { kc = slice * 2 + (l >> 2); q = l & 3; }
    else          { kc = slice;                q = l;     }
    *(VU*)(out + (blkb + kc) * 8192 + pk_idx(rr, q)) = o;
}

// ---------------------------------------------------------------------------
__launch_bounds__(1024)
__global__ void fc1_head(const float* __restrict__ sums, const int* __restrict__ batch,
                         const float* __restrict__ fc1_w, const float* __restrict__ fc1_b,
                         const float* __restrict__ head_w, const float* __restrict__ head_b,
                         float* __restrict__ out) {
    __shared__ float sv[D_HID];
    __shared__ float hacc[N_CLS];
    __shared__ float invc;
    int g = blockIdx.x;
    int t = threadIdx.x;
    if (t == 0) {
        int lo = 0, hi = N_NODES;
        while (lo < hi) { int m = (lo + hi) >> 1; if (batch[m] < g) lo = m + 1; else hi = m; }
        int lb = lo;
        lo = lb; hi = N_NODES;
        while (lo < hi) { int m = (lo + hi) >> 1; if (batch[m] < g + 1) lo = m + 1; else hi = m; }
        invc = 1.f / fmaxf((float)(lo - lb), 1.f);
    }
    if (t < N_CLS) hacc[t] = 0.f;
    __syncthreads();
    if (t < D_HID) sv[t] = sums[(size_t)g * D_HID + t] * invc;
    __syncthreads();
    int j = t;                      // D_FC == blockDim
    float acc = fc1_b[j];
#pragma unroll 8
    for (int k = 0; k < D_HID; ++k) acc += sv[k] * fc1_w[(size_t)k * D_FC + j];
    float f = fmaxf(acc, 0.f);
    float p[N_CLS];
#pragma unroll
    for (int c = 0; c < N_CLS; ++c) p[c] = f * head_w[j * N_CLS + c];
#pragma unroll
    for (int c = 0; c < N_CLS; ++c) {
        float v = p[c];
        for (int off = 32; off; off >>= 1) v += __shfl_down(v, off, 64);
        if ((t & 63) == 0) atomicAdd(&hacc[c], v);
    }
    __syncthreads();
    if (t < N_CLS) out[g * N_CLS + t] = hacc[t] + head_b[t];
}

extern "C" void kernel_launch(void* const* d_in, const int* in_sizes, int n_in,
                              void* d_out, int out_size, void* d_ws, size_t ws_size,
                              hipStream_t stream) {
    const float* x          = (const float*)d_in[0];
    const int*   edge_index = (const int*)d_in[1];
    const float* edge_attr  = (const float*)d_in[2];
    const int*   batch      = (const int*)d_in[3];
    const float* emb_w1 = (const float*)d_in[4];
    const float* emb_b1 = (const float*)d_in[5];
    const float* emb_w2 = (const float*)d_in[6];
    const float* emb_b2 = (const float*)d_in[7];
    const float* ep_w1  = (const float*)d_in[8];
    const float* ep_b1  = (const float*)d_in[9];
    const float* ep_w2  = (const float*)d_in[10];
    const float* ep_b2  = (const float*)d_in[11];
    const float* w_c[6] = { (const float*)d_in[12], (const float*)d_in[14], (const float*)d_in[16],
                            (const float*)d_in[18], (const float*)d_in[20], (const float*)d_in[22] };
    const float* b_c[6] = { (const float*)d_in[13], (const float*)d_in[15], (const float*)d_in[17],
                            (const float*)d_in[19], (const float*)d_in[21], (const float*)d_in[23] };
    const float* fc1_w  = (const float*)d_in[24];
    const float* fc1_b  = (const float*)d_in[25];
    const float* head_w = (const float*)d_in[26];
    const float* head_b = (const float*)d_in[27];
    float* out = (float*)d_out;

    const int* src = edge_index;
    const int* dst = edge_index + N_EDGES;

    char* p = (char*)d_ws;
    auto alloc = [&](size_t bytes) { char* r = p; p += (bytes + 255) & ~(size_t)255; return r; };
    float* ew    = (float*)alloc(N_EDGES * 4);
    float* deg   = (float*)alloc(N_NODES * 4);
    float* dinv  = (float*)alloc(N_NODES * 4);
    float* nloop = (float*)alloc(N_NODES * 4);
    int* cnt     = (int*)alloc(N_NODES * 4);
    int* cursor  = (int*)alloc(N_NODES * 4);
    int* rowptr  = (int*)alloc((N_NODES + 1) * 4);
    int2* cv     = (int2*)alloc((size_t)N_EDGES * 8);
    u16* xb = (u16*)alloc((size_t)MP * F_IN * 2);
    u16* H1 = (u16*)alloc((size_t)MP * D_EMB * 2);
    u16* H2 = (u16*)alloc((size_t)MP * D_EMB * 2);
    u16* G  = (u16*)alloc((size_t)MP * D_HID * 2);
    u16* S1 = (u16*)alloc((size_t)MP * D_HID * 2);
    u16* S2 = (u16*)alloc((size_t)MP * D_HID * 2);
    u16* Cb = (u16*)alloc((size_t)MP * D_HID * 2);
    u16* we1 = (u16*)alloc((size_t)F_IN * D_EMB * 2);
    u16* we2 = (u16*)alloc((size_t)D_EMB * D_EMB * 2);
    u16* wc[6];
    wc[0] = (u16*)alloc((size_t)D_EMB * D_HID * 2);
    for (int i = 1; i < 6; ++i) wc[i] = (u16*)alloc((size_t)D_HID * D_HID * 2);
    float* sums = (float*)alloc(N_GRAPHS * D_HID * 4);

    const int TB = 256;
    const int EB = (N_EDGES + TB - 1) / TB;
    const int NB = (N_NODES + TB - 1) / TB;

    prep_all<<<(MP * F_IN + TB - 1) / TB, TB, 0, stream>>>(x, xb, G, deg, cnt, cursor, sums);
    edge_mlp_deg<<<EB, TB, 0, stream>>>(edge_attr, ep_w1, ep_b1, ep_w2, ep_b2, dst, ew, deg, cnt);
    dinv_kernel<<<NB, TB, 0, stream>>>(deg, dinv, nloop);
    scan_kernel<<<1, 1024, 0, stream>>>(cnt, rowptr);
    fill_csr_kernel<<<EB, TB, 0, stream>>>(src, dst, ew, dinv, rowptr, cursor, cv);

    WP8 wp;
    wp.m[0] = { emb_w1, we1, F_IN,  D_EMB };
    wp.m[1] = { emb_w2, we2, D_EMB, D_EMB };
    wp.m[2] = { w_c[0], wc[0], D_EMB, D_HID };
    for (int i = 1; i < 6; ++i) wp.m[2 + i] = { w_c[i], wc[i], D_HID, D_HID };
    wprep_all<<<dim3(16, 16, 8), dim3(32, 8), 0, stream>>>(wp);

    const int SLOTS = ((NROWB + 7) / 8) * 8;        // 160
    const int GRID2 = SLOTS * (D_EMB / 64);         // 640
    const int GRID4 = SLOTS * (D_HID / 64);         // 1280
    // GEMM1: xb packed -> H1 PACKED (A of GEMM2)
    mfma_gemm<<<GRID2, 512, 0, stream>>>(xb, we1, emb_b1, nullptr, nullptr, H1, F_IN, D_EMB, nullptr, nullptr);
    // GEMM2: H1 packed -> H2 row-major (gather input)
    mfma_gemm<<<GRID2, 512, 0, stream>>>(H1, we2, emb_b2, nullptr, H2, nullptr, D_EMB, D_EMB, nullptr, nullptr);

    const int GG256 = (N_NODES / 64) * 8;           // 5000 (D=256: 64 nodes/block)
    const int GG512 = (N_NODES / 32) * 8;           // 10000 (D=512: 32 nodes/block)
    gather_f16<D_EMB><<<GG256, 256, 0, stream>>>(H2, rowptr, cv, nloop, G);
    mfma_gemm<<<GRID4, 512, 0, stream>>>(G, wc[0], b_c[0], nullptr, S1, nullptr, D_EMB, D_HID, nullptr, nullptr);
    gather_f16<D_HID><<<GG512, 256, 0, stream>>>(S1, rowptr, cv, nloop, G);
    mfma_gemm<<<GRID4, 512, 0, stream>>>(G, wc[1], b_c[1], nullptr, Cb, nullptr, D_HID, D_HID, nullptr, nullptr);
    gather_f16<D_HID><<<GG512, 256, 0, stream>>>(Cb, rowptr, cv, nloop, G);
    mfma_gemm<<<GRID4, 512, 0, stream>>>(G, wc[2], b_c[2], S1, S2, nullptr, D_HID, D_HID, nullptr, nullptr);
    gather_f16<D_HID><<<GG512, 256, 0, stream>>>(S2, rowptr, cv, nloop, G);
    mfma_gemm<<<GRID4, 512, 0, stream>>>(G, wc[3], b_c[3], nullptr, Cb, nullptr, D_HID, D_HID, nullptr, nullptr);
    gather_f16<D_HID><<<GG512, 256, 0, stream>>>(Cb, rowptr, cv, nloop, G);
    mfma_gemm<<<GRID4, 512, 0, stream>>>(G, wc[4], b_c[4], nullptr, Cb, nullptr, D_HID, D_HID, nullptr, nullptr);
    gather_f16<D_HID><<<GG512, 256, 0, stream>>>(Cb, rowptr, cv, nloop, G);
    // final layer: fused mean-pool epilogue, no store
    mfma_gemm<<<GRID4, 512, 0, stream>>>(G, wc[5], b_c[5], S2, nullptr, nullptr, D_HID, D_HID, batch, sums);

    fc1_head<<<N_GRAPHS, 1024, 0, stream>>>(sums, batch, fc1_w, fc1_b, head_w, head_b, out);
}

// Round 12
// 1020.307 us; speedup vs baseline: 1.0139x; 1.0139x over previous
//
#include <hip/hip_runtime.h>
#include <math.h>

#define N_NODES 40000
#define MP      40192   // 157 * 256
#define NROWB   157
#define N_EDGES 640000
#define N_GRAPHS 64
#define F_IN 32
#define D_EMB 256
#define D_HID 512
#define D_FC 1024
#define N_CLS 10

typedef _Float16 f16x8 __attribute__((ext_vector_type(8)));
typedef float f32x4  __attribute__((ext_vector_type(4)));
typedef unsigned short u16;

template <int N> struct VecU;
template <> struct VecU<2> { typedef unsigned T __attribute__((ext_vector_type(2))); };
template <> struct VecU<4> { typedef unsigned T __attribute__((ext_vector_type(4))); };
typedef VecU<4>::T u32x4;

__device__ __forceinline__ float h2f(u16 u) {
    union { u16 s; _Float16 h; } v; v.s = u; return (float)v.h;
}
__device__ __forceinline__ u16 f2h(float f) {
    union { u16 s; _Float16 h; } v; v.h = (_Float16)f; return v.s;
}
// R20: one-instruction f16xf32+f32 FMA pair (lo/hi of a packed u32) —
// bit-identical to cvt+fmac at half the VALU issue count.
__device__ __forceinline__ void fma_mix2(float& a0, float& a1, unsigned u, float v) {
    asm("v_fma_mix_f32 %0, %2, %3, %0 op_sel:[0,0,0] op_sel_hi:[1,0,0]\n\t"
        "v_fma_mix_f32 %1, %2, %3, %1 op_sel:[1,0,0] op_sel_hi:[1,0,0]"
        : "+v"(a0), "+v"(a1) : "v"(u), "v"(v));
}
// R24: inline-asm 16B global load — the compiler collapsed named-register
// prefetch 3x (VGPR 52/48 at depth 2/6); asm outputs cannot be collapsed,
// so the in-flight window finally materializes in hardware.
__device__ __forceinline__ void gl16(u32x4& d, const u16* p) {
    asm volatile("global_load_dwordx4 %0, %1, off" : "=v"(d) : "v"(p) : "memory");
}
__device__ __forceinline__ f16x8 bc(u32x4 v) { return __builtin_bit_cast(f16x8, v); }

// ---------------------------------------------------------------------------
// Packed operand layout (R16): A as 256-row x 32-k 16KB chunks (XOR-swizzled
// image); W as 128-row x 32-k 8KB tiles. pk_idx = u16 offset of (row, quad).
// R24 GEMM K-loop: asm ping-pong loads + manual s_waitcnt vmcnt(6) (never 0
// in steady state) — AITER-style counted-vmcnt that hipcc won't emit from
// C++ source. Zero barriers, zero LDS in the K-loop.
// ---------------------------------------------------------------------------
__device__ __forceinline__ int pk_idx(int r, int q) {
    int rp = r >> 1;
    int g  = (((r & 1) << 2) | q) ^ (rp & 7);
    return rp * 64 + g * 8;
}

__global__ void prep_all(const float* __restrict__ x, u16* __restrict__ xb, u16* __restrict__ G,
                         float* __restrict__ deg, int* __restrict__ cnt, int* __restrict__ cursor,
                         float* __restrict__ sums) {
    int i = blockIdx.x * blockDim.x + threadIdx.x;
    if (i < N_NODES) { deg[i] = 1.0f; cnt[i] = 0; cursor[i] = 0; }
    if (i < MP * F_IN) {
        int row = i >> 5, colk = i & 31;
        float v = (row < N_NODES) ? x[i] : 0.f;
        size_t idx = (size_t)(row >> 8) * 8192 + pk_idx(row & 255, colk >> 3) + (colk & 7);
        xb[idx] = f2h(v);
    }
    if (i < 16 * 3072) {                     // 512-packed pad rows (rowblk 156, rows 160..255)
        int kc = i / 3072, rem = i % 3072;
        G[(size_t)(156 * 16 + kc) * 8192 + 5120 + rem] = 0;
    } else if (i < 16 * 3072 + 8 * 3072) {   // 256-packed pad rows
        int j = i - 16 * 3072;
        int kc = j / 3072, rem = j % 3072;
        G[(size_t)(156 * 8 + kc) * 8192 + 5120 + rem] = 0;
    }
    if (i < N_GRAPHS * D_HID) sums[i] = 0.f;
}

__global__ void edge_mlp_deg(const float* __restrict__ edge_attr,
                             const float* __restrict__ ep_w1, const float* __restrict__ ep_b1,
                             const float* __restrict__ ep_w2, const float* __restrict__ ep_b2,
                             const int* __restrict__ dst,
                             float* __restrict__ ew, float* __restrict__ deg, int* __restrict__ cnt) {
    __shared__ float w1[64], b1[64], w2[64];
    int t = threadIdx.x;
    if (t < 64) { w1[t] = ep_w1[t]; b1[t] = ep_b1[t]; w2[t] = ep_w2[t]; }
    __syncthreads();
    int e = blockIdx.x * blockDim.x + t;
    if (e >= N_EDGES) return;
    float x = edge_attr[e];
    float s = ep_b2[0];
#pragma unroll
    for (int j = 0; j < 64; ++j) s += fmaxf(x * w1[j] + b1[j], 0.f) * w2[j];
    float sig = 1.f / (1.f + expf(-s));
    ew[e] = sig;
    int d = dst[e];
    atomicAdd(&deg[d], sig);
    atomicAdd(&cnt[d], 1);
}

__global__ void dinv_kernel(const float* __restrict__ deg, float* __restrict__ dinv,
                            float* __restrict__ nloop) {
    int i = blockIdx.x * blockDim.x + threadIdx.x;
    if (i >= N_NODES) return;
    float d = deg[i];
    float r = (d > 0.f) ? rsqrtf(fmaxf(d, 1e-12f)) : 0.f;
    dinv[i] = r;
    nloop[i] = r * r;
}

__global__ void scan_kernel(const int* __restrict__ cnt, int* __restrict__ rowptr) {
    __shared__ int part[1024];
    int t = threadIdx.x;
    const int PER = (N_NODES + 1023) / 1024;
    int base = t * PER;
    int s = 0;
    for (int k = 0; k < PER; ++k) { int i = base + k; if (i < N_NODES) s += cnt[i]; }
    part[t] = s;
    __syncthreads();
    for (int off = 1; off < 1024; off <<= 1) {
        int v = (t >= off) ? part[t - off] : 0;
        __syncthreads();
        part[t] += v;
        __syncthreads();
    }
    int run = (t == 0) ? 0 : part[t - 1];
    for (int k = 0; k < PER; ++k) {
        int i = base + k;
        if (i < N_NODES) { rowptr[i] = run; run += cnt[i]; }
    }
    if (t == 1023) rowptr[N_NODES] = run;
}

__global__ void fill_csr_kernel(const int* __restrict__ src, const int* __restrict__ dst,
                                const float* __restrict__ ew, const float* __restrict__ dinv,
                                const int* __restrict__ rowptr, int* __restrict__ cursor,
                                int2* __restrict__ cv) {
    int e = blockIdx.x * blockDim.x + threadIdx.x;
    if (e >= N_EDGES) return;
    int d = dst[e];
    int s = src[e];
    float n = dinv[s] * ew[e] * dinv[d];
    int p = rowptr[d] + atomicAdd(&cursor[d], 1);
    cv[p] = make_int2(s, __float_as_int(n));
}

// ---------------------------------------------------------------------------
struct WPair { const float* s; u16* d; int K; int N; };
struct WP8 { WPair m[8]; };

__global__ void wprep_all(WP8 a) {
    __shared__ u16 th[32][33];
    WPair w = a.m[blockIdx.z];
    int n0 = blockIdx.x * 32;
    int k0 = blockIdx.y * 32;
    if (n0 >= w.N || k0 >= w.K) return;
    int tx = threadIdx.x, ty = threadIdx.y;
#pragma unroll
    for (int r = 0; r < 4; ++r) {
        int k = ty + r * 8;
        th[k][tx] = f2h(w.s[(size_t)(k0 + k) * w.N + n0 + tx]);
    }
    __syncthreads();
#pragma unroll
    for (int r = 0; r < 4; ++r) {
        int n = ty + r * 8;
        int R = n0 + n;
        int kcol = k0 + tx;
        size_t idx = ((size_t)(R >> 7) * (w.K >> 5) + (kcol >> 5)) * 4096
                   + pk_idx(R & 127, (kcol >> 3) & 3) + (kcol & 7);
        w.d[idx] = th[tx][n];
    }
}

// ---------------------------------------------------------------------------
// R24 GEMM: BM=256 x BN=64, 512 threads. K-loop: asm ping-pong register sets
// A/B, 6x1KB loads issued per step via inline asm, manual vmcnt(6) before
// each MFMA octet (never draining in steady state). No LDS, no barriers in
// the K-loop. Single-pass epilogue (37KB LDS). C / Cpk / pool paths.
// ---------------------------------------------------------------------------
__launch_bounds__(512)
__global__ void mfma_gemm(const u16* __restrict__ A,
                          const u16* __restrict__ W,
                          const float* __restrict__ bias,
                          const u16* __restrict__ skip,
                          u16* __restrict__ C, u16* __restrict__ Cpk,
                          int K, int N,
                          const int* __restrict__ batch, float* __restrict__ pool) {
    __shared__ __align__(16) u16 eb[256 * 72];   // 36.9 KB epilogue buffer
    __shared__ int sbatch[256];

    const int nColB = N >> 6;
    int b = blockIdx.x;
    int rowI = (b >> 3) / nColB * 8 + (b & 7);
    int colI = (b >> 3) % nColB;
    if (rowI >= NROWB) return;
    int rowBase = rowI * 256;
    int colBase = colI * 64;

    int t = threadIdx.x;
    int lane = t & 63;
    int wave = t >> 6;          // owns rows wave*32 .. +32
    int quad = lane >> 4;
    int mrow = lane & 15;
    int nIter = K >> 5;

    // per-lane swizzled granule offset (identical for A and W packed reads)
    int sw = (((mrow & 1) << 2) | quad) ^ ((mrow >> 1) & 7);
    int laneA = (wave * 16 + (mrow >> 1)) * 64 + sw * 8;   // wave's 32-row strip
    int laneW = (mrow >> 1) * 64 + sw * 8;                 // col-tile j adds j*512

    const u16* pA = A + (size_t)rowI * nIter * 8192;
    const u16* pW = W + ((size_t)(colI >> 1) * nIter) * 4096 + (colI & 1) * 2048;

    u32x4 aa0, aa1, aw0, aw1, aw2, aw3;   // ping set
    u32x4 ba0, ba1, bw0, bw1, bw2, bw3;   // pong set

    // prologue: issue step-0 loads into A set (6 in flight)
    gl16(aa0, pA + laneA);
    gl16(aa1, pA + laneA + 512);
    gl16(aw0, pW + laneW);
    gl16(aw1, pW + laneW + 512);
    gl16(aw2, pW + laneW + 1024);
    gl16(aw3, pW + laneW + 1536);

    f32x4 acc[2][4] = {};

    for (int it = 0; it < nIter; it += 2) {
        if (it + 1 < nIter) {           // issue step it+1 into B set; wait A set
            const u16* A1 = pA + (size_t)(it + 1) * 8192;
            const u16* W1 = pW + (size_t)(it + 1) * 4096;
            gl16(ba0, A1 + laneA);
            gl16(ba1, A1 + laneA + 512);
            gl16(bw0, W1 + laneW);
            gl16(bw1, W1 + laneW + 512);
            gl16(bw2, W1 + laneW + 1024);
            gl16(bw3, W1 + laneW + 1536);
            asm volatile("s_waitcnt vmcnt(6)" ::: "memory");
        } else {
            asm volatile("s_waitcnt vmcnt(0)" ::: "memory");
        }
        __builtin_amdgcn_sched_barrier(0);
        {
            f16x8 a0 = bc(aa0), a1 = bc(aa1);
            f16x8 w0 = bc(aw0), w1 = bc(aw1), w2 = bc(aw2), w3 = bc(aw3);
            acc[0][0] = __builtin_amdgcn_mfma_f32_16x16x32_f16(a0, w0, acc[0][0], 0, 0, 0);
            acc[1][0] = __builtin_amdgcn_mfma_f32_16x16x32_f16(a1, w0, acc[1][0], 0, 0, 0);
            acc[0][1] = __builtin_amdgcn_mfma_f32_16x16x32_f16(a0, w1, acc[0][1], 0, 0, 0);
            acc[1][1] = __builtin_amdgcn_mfma_f32_16x16x32_f16(a1, w1, acc[1][1], 0, 0, 0);
            acc[0][2] = __builtin_amdgcn_mfma_f32_16x16x32_f16(a0, w2, acc[0][2], 0, 0, 0);
            acc[1][2] = __builtin_amdgcn_mfma_f32_16x16x32_f16(a1, w2, acc[1][2], 0, 0, 0);
            acc[0][3] = __builtin_amdgcn_mfma_f32_16x16x32_f16(a0, w3, acc[0][3], 0, 0, 0);
            acc[1][3] = __builtin_amdgcn_mfma_f32_16x16x32_f16(a1, w3, acc[1][3], 0, 0, 0);
        }
        if (it + 1 < nIter) {
            if (it + 2 < nIter) {       // issue step it+2 into A set; wait B set
                const u16* A2 = pA + (size_t)(it + 2) * 8192;
                const u16* W2 = pW + (size_t)(it + 2) * 4096;
                gl16(aa0, A2 + laneA);
                gl16(aa1, A2 + laneA + 512);
                gl16(aw0, W2 + laneW);
                gl16(aw1, W2 + laneW + 512);
                gl16(aw2, W2 + laneW + 1024);
                gl16(aw3, W2 + laneW + 1536);
                asm volatile("s_waitcnt vmcnt(6)" ::: "memory");
            } else {
                asm volatile("s_waitcnt vmcnt(0)" ::: "memory");
            }
            __builtin_amdgcn_sched_barrier(0);
            f16x8 a0 = bc(ba0), a1 = bc(ba1);
            f16x8 w0 = bc(bw0), w1 = bc(bw1), w2 = bc(bw2), w3 = bc(bw3);
            acc[0][0] = __builtin_amdgcn_mfma_f32_16x16x32_f16(a0, w0, acc[0][0], 0, 0, 0);
            acc[1][0] = __builtin_amdgcn_mfma_f32_16x16x32_f16(a1, w0, acc[1][0], 0, 0, 0);
            acc[0][1] = __builtin_amdgcn_mfma_f32_16x16x32_f16(a0, w1, acc[0][1], 0, 0, 0);
            acc[1][1] = __builtin_amdgcn_mfma_f32_16x16x32_f16(a1, w1, acc[1][1], 0, 0, 0);
            acc[0][2] = __builtin_amdgcn_mfma_f32_16x16x32_f16(a0, w2, acc[0][2], 0, 0, 0);
            acc[1][2] = __builtin_amdgcn_mfma_f32_16x16x32_f16(a1, w2, acc[1][2], 0, 0, 0);
            acc[0][3] = __builtin_amdgcn_mfma_f32_16x16x32_f16(a0, w3, acc[0][3], 0, 0, 0);
            acc[1][3] = __builtin_amdgcn_mfma_f32_16x16x32_f16(a1, w3, acc[1][3], 0, 0, 0);
        }
    }

    // ---- single-pass epilogue ----
    const int ES = 72;                              // 144B rows, 16B-aligned
#pragma unroll
    for (int j = 0; j < 4; ++j) {
        int col = colBase + j * 16 + mrow;
        float bv = bias[col];
#pragma unroll
        for (int i = 0; i < 2; ++i) {
#pragma unroll
            for (int r = 0; r < 4; ++r) {
                int lr = wave * 32 + i * 16 + quad * 4 + r;
                size_t row = (size_t)rowBase + lr;
                float v = fmaxf(acc[i][j][r] + bv, 0.f);
                if (skip) v += h2f(skip[row * N + col]);
                eb[lr * ES + j * 16 + mrow] = f2h(v);
            }
        }
    }
    if (pool && t < 256) {
        int row = rowBase + t;
        sbatch[t] = (row < N_NODES) ? batch[row] : -1;
    }
    __syncthreads();
    if (C) {
#pragma unroll
        for (int k2 = 0; k2 < 4; ++k2) {
            int c = t + k2 * 512;
            int row = c >> 3, ch = c & 7;
            f16x8 v = *(const f16x8*)&eb[row * ES + ch * 8];
            *(f16x8*)&C[(size_t)(rowBase + row) * N + colBase + ch * 8] = v;
        }
    } else if (Cpk) {
#pragma unroll
        for (int k2 = 0; k2 < 4; ++k2) {
            int c = t + k2 * 512;
            int row = c >> 3, ch = c & 7;
            f16x8 v = *(const f16x8*)&eb[row * ES + ch * 8];
            size_t idx = ((size_t)rowI * (N >> 5) + (colBase >> 5) + (ch >> 2)) * 8192
                       + pk_idx(row, ch & 3);
            *(f16x8*)&Cpk[idx] = v;
        }
    }
    if (pool) {
        int c = t & 63;
        int rs = (t >> 6) * 32;
        float run = 0.f; int g = -1;
        for (int r = rs; r < rs + 32; ++r) {
            int bg = sbatch[r];
            if (bg != g) {
                if (g >= 0) atomicAdd(&pool[(size_t)g * D_HID + colBase + c], run);
                run = 0.f; g = bg;
            }
            if (bg >= 0) run += h2f(eb[r * ES + c]);
        }
        if (g >= 0) atomicAdd(&pool[(size_t)g * D_HID + colBase + c], run);
    }
}

// ---------------------------------------------------------------------------
// R19 gather: XCD column-sliced; R20: fma_mix accumulate. Output packed.
// ---------------------------------------------------------------------------
template <int D>
__launch_bounds__(256)
__global__ void gather_f16(const u16* __restrict__ h, const int* __restrict__ rowptr,
                           const int2* __restrict__ cv, const float* __restrict__ nloop,
                           u16* __restrict__ out) {
    constexpr int COLS = D / 8;       // cols per XCD slice (64 / 32)
    constexpr int LPG  = COLS / 8;    // lanes per node sub-group (8 / 4)
    constexpr int NPB  = 256 / LPG;   // nodes per block (32 / 64)
    using VU = typename VecU<4>::T;   // 16B = 8 f16
    int b = blockIdx.x;
    int slice = b & 7;
    int ng = b >> 3;
    int t = threadIdx.x;
    int node = ng * NPB + t / LPG;
    int l = t % LPG;
    if (node >= N_NODES) return;
    const u16* hs = h + slice * COLS + l * 8;   // per-lane 8-col window
    float acc[8];
    float sl = nloop[node];
    {
        VU own = *(const VU*)(hs + (size_t)node * D);
#pragma unroll
        for (int u = 0; u < 4; ++u) {
            acc[2 * u] = 0.f; acc[2 * u + 1] = 0.f;
            fma_mix2(acc[2 * u], acc[2 * u + 1], own[u], sl);
        }
    }
    int beg = rowptr[node], end = rowptr[node + 1];
    if (end > beg) {
        int last = end - 1;
        int2 c[8];
#pragma unroll
        for (int m = 0; m < 8; ++m) c[m] = cv[min(beg + m, last)];
        for (int j = beg; j < end; j += 8) {
            VU tv[8];
#pragma unroll
            for (int m = 0; m < 8; ++m)
                tv[m] = *(const VU*)(hs + (size_t)c[m].x * D);
            int jn = j + 8;
            int2 cn[8];
#pragma unroll
            for (int m = 0; m < 8; ++m) cn[m] = c[m];
            if (jn < end) {
#pragma unroll
                for (int m = 0; m < 8; ++m) cn[m] = cv[min(jn + m, last)];
            }
            __builtin_amdgcn_sched_barrier(0);
#pragma unroll
            for (int m = 0; m < 8; ++m) {
                float v = (j + m < end) ? __int_as_float(c[m].y) : 0.f;
#pragma unroll
                for (int u = 0; u < 4; ++u)
                    fma_mix2(acc[2 * u], acc[2 * u + 1], tv[m][u], v);
            }
#pragma unroll
            for (int m = 0; m < 8; ++m) c[m] = cn[m];
        }
    }
    VU o;
#pragma unroll
    for (int u = 0; u < 4; ++u) {
        unsigned lo = f2h(acc[2 * u]);
        unsigned hi = f2h(acc[2 * u + 1]);
        o[u] = lo | (hi << 16);
    }
    size_t blkb = (size_t)(node >> 8) * (D >> 5);
    int rr = node & 255;
    int kc, q;
    if (D == 512) { kc = slice * 2 + (l >> 2); q = l & 3; }
    else          { kc = slice;                q = l;     }
    *(VU*)(out + (blkb + kc) * 8192 + pk_idx(rr, q)) = o;
}

// ---------------------------------------------------------------------------
__launch_bounds__(1024)
__global__ void fc1_head(const float* __restrict__ sums, const int* __restrict__ batch,
                         const float* __restrict__ fc1_w, const float* __restrict__ fc1_b,
                         const float* __restrict__ head_w, const float* __restrict__ head_b,
                         float* __restrict__ out) {
    __shared__ float sv[D_HID];
    __shared__ float hacc[N_CLS];
    __shared__ float invc;
    int g = blockIdx.x;
    int t = threadIdx.x;
    if (t == 0) {
        int lo = 0, hi = N_NODES;
        while (lo < hi) { int m = (lo + hi) >> 1; if (batch[m] < g) lo = m + 1; else hi = m; }
        int lb = lo;
        lo = lb; hi = N_NODES;
        while (lo < hi) { int m = (lo + hi) >> 1; if (batch[m] < g + 1) lo = m + 1; else hi = m; }
        invc = 1.f / fmaxf((float)(lo - lb), 1.f);
    }
    if (t < N_CLS) hacc[t] = 0.f;
    __syncthreads();
    if (t < D_HID) sv[t] = sums[(size_t)g * D_HID + t] * invc;
    __syncthreads();
    int j = t;                      // D_FC == blockDim
    float acc = fc1_b[j];
#pragma unroll 8
    for (int k = 0; k < D_HID; ++k) acc += sv[k] * fc1_w[(size_t)k * D_FC + j];
    float f = fmaxf(acc, 0.f);
    float p[N_CLS];
#pragma unroll
    for (int c = 0; c < N_CLS; ++c) p[c] = f * head_w[j * N_CLS + c];
#pragma unroll
    for (int c = 0; c < N_CLS; ++c) {
        float v = p[c];
        for (int off = 32; off; off >>= 1) v += __shfl_down(v, off, 64);
        if ((t & 63) == 0) atomicAdd(&hacc[c], v);
    }
    __syncthreads();
    if (t < N_CLS) out[g * N_CLS + t] = hacc[t] + head_b[t];
}

extern "C" void kernel_launch(void* const* d_in, const int* in_sizes, int n_in,
                              void* d_out, int out_size, void* d_ws, size_t ws_size,
                              hipStream_t stream) {
    const float* x          = (const float*)d_in[0];
    const int*   edge_index = (const int*)d_in[1];
    const float* edge_attr  = (const float*)d_in[2];
    const int*   batch      = (const int*)d_in[3];
    const float* emb_w1 = (const float*)d_in[4];
    const float* emb_b1 = (const float*)d_in[5];
    const float* emb_w2 = (const float*)d_in[6];
    const float* emb_b2 = (const float*)d_in[7];
    const float* ep_w1  = (const float*)d_in[8];
    const float* ep_b1  = (const float*)d_in[9];
    const float* ep_w2  = (const float*)d_in[10];
    const float* ep_b2  = (const float*)d_in[11];
    const float* w_c[6] = { (const float*)d_in[12], (const float*)d_in[14], (const float*)d_in[16],
                            (const float*)d_in[18], (const float*)d_in[20], (const float*)d_in[22] };
    const float* b_c[6] = { (const float*)d_in[13], (const float*)d_in[15], (const float*)d_in[17],
                            (const float*)d_in[19], (const float*)d_in[21], (const float*)d_in[23] };
    const float* fc1_w  = (const float*)d_in[24];
    const float* fc1_b  = (const float*)d_in[25];
    const float* head_w = (const float*)d_in[26];
    const float* head_b = (const float*)d_in[27];
    float* out = (float*)d_out;

    const int* src = edge_index;
    const int* dst = edge_index + N_EDGES;

    char* p = (char*)d_ws;
    auto alloc = [&](size_t bytes) { char* r = p; p += (bytes + 255) & ~(size_t)255; return r; };
    float* ew    = (float*)alloc(N_EDGES * 4);
    float* deg   = (float*)alloc(N_NODES * 4);
    float* dinv  = (float*)alloc(N_NODES * 4);
    float* nloop = (float*)alloc(N_NODES * 4);
    int* cnt     = (int*)alloc(N_NODES * 4);
    int* cursor  = (int*)alloc(N_NODES * 4);
    int* rowptr  = (int*)alloc((N_NODES + 1) * 4);
    int2* cv     = (int2*)alloc((size_t)N_EDGES * 8);
    u16* xb = (u16*)alloc((size_t)MP * F_IN * 2);
    u16* H1 = (u16*)alloc((size_t)MP * D_EMB * 2);
    u16* H2 = (u16*)alloc((size_t)MP * D_EMB * 2);
    u16* G  = (u16*)alloc((size_t)MP * D_HID * 2);
    u16* S1 = (u16*)alloc((size_t)MP * D_HID * 2);
    u16* S2 = (u16*)alloc((size_t)MP * D_HID * 2);
    u16* Cb = (u16*)alloc((size_t)MP * D_HID * 2);
    u16* we1 = (u16*)alloc((size_t)F_IN * D_EMB * 2);
    u16* we2 = (u16*)alloc((size_t)D_EMB * D_EMB * 2);
    u16* wc[6];
    wc[0] = (u16*)alloc((size_t)D_EMB * D_HID * 2);
    for (int i = 1; i < 6; ++i) wc[i] = (u16*)alloc((size_t)D_HID * D_HID * 2);
    float* sums = (float*)alloc(N_GRAPHS * D_HID * 4);

    const int TB = 256;
    const int EB = (N_EDGES + TB - 1) / TB;
    const int NB = (N_NODES + TB - 1) / TB;

    prep_all<<<(MP * F_IN + TB - 1) / TB, TB, 0, stream>>>(x, xb, G, deg, cnt, cursor, sums);
    edge_mlp_deg<<<EB, TB, 0, stream>>>(edge_attr, ep_w1, ep_b1, ep_w2, ep_b2, dst, ew, deg, cnt);
    dinv_kernel<<<NB, TB, 0, stream>>>(deg, dinv, nloop);
    scan_kernel<<<1, 1024, 0, stream>>>(cnt, rowptr);
    fill_csr_kernel<<<EB, TB, 0, stream>>>(src, dst, ew, dinv, rowptr, cursor, cv);

    WP8 wp;
    wp.m[0] = { emb_w1, we1, F_IN,  D_EMB };
    wp.m[1] = { emb_w2, we2, D_EMB, D_EMB };
    wp.m[2] = { w_c[0], wc[0], D_EMB, D_HID };
    for (int i = 1; i < 6; ++i) wp.m[2 + i] = { w_c[i], wc[i], D_HID, D_HID };
    wprep_all<<<dim3(16, 16, 8), dim3(32, 8), 0, stream>>>(wp);

    const int SLOTS = ((NROWB + 7) / 8) * 8;        // 160
    const int GRID2 = SLOTS * (D_EMB / 64);         // 640
    const int GRID4 = SLOTS * (D_HID / 64);         // 1280
    // GEMM1: xb packed -> H1 PACKED (A of GEMM2)
    mfma_gemm<<<GRID2, 512, 0, stream>>>(xb, we1, emb_b1, nullptr, nullptr, H1, F_IN, D_EMB, nullptr, nullptr);
    // GEMM2: H1 packed -> H2 row-major (gather input)
    mfma_gemm<<<GRID2, 512, 0, stream>>>(H1, we2, emb_b2, nullptr, H2, nullptr, D_EMB, D_EMB, nullptr, nullptr);

    const int GG256 = (N_NODES / 64) * 8;           // 5000 (D=256: 64 nodes/block)
    const int GG512 = (N_NODES / 32) * 8;           // 10000 (D=512: 32 nodes/block)
    gather_f16<D_EMB><<<GG256, 256, 0, stream>>>(H2, rowptr, cv, nloop, G);
    mfma_gemm<<<GRID4, 512, 0, stream>>>(G, wc[0], b_c[0], nullptr, S1, nullptr, D_EMB, D_HID, nullptr, nullptr);
    gather_f16<D_HID><<<GG512, 256, 0, stream>>>(S1, rowptr, cv, nloop, G);
    mfma_gemm<<<GRID4, 512, 0, stream>>>(G, wc[1], b_c[1], nullptr, Cb, nullptr, D_HID, D_HID, nullptr, nullptr);
    gather_f16<D_HID><<<GG512, 256, 0, stream>>>(Cb, rowptr, cv, nloop, G);
    mfma_gemm<<<GRID4, 512, 0, stream>>>(G, wc[2], b_c[2], S1, S2, nullptr, D_HID, D_HID, nullptr, nullptr);
    gather_f16<D_HID><<<GG512, 256, 0, stream>>>(S2, rowptr, cv, nloop, G);
    mfma_gemm<<<GRID4, 512, 0, stream>>>(G, wc[3], b_c[3], nullptr, Cb, nullptr, D_HID, D_HID, nullptr, nullptr);
    gather_f16<D_HID><<<GG512, 256, 0, stream>>>(Cb, rowptr, cv, nloop, G);
    mfma_gemm<<<GRID4, 512, 0, stream>>>(G, wc[4], b_c[4], nullptr, Cb, nullptr, D_HID, D_HID, nullptr, nullptr);
    gather_f16<D_HID><<<GG512, 256, 0, stream>>>(Cb, rowptr, cv, nloop, G);
    // final layer: fused mean-pool epilogue, no store
    mfma_gemm<<<GRID4, 512, 0, stream>>>(G, wc[5], b_c[5], S2, nullptr, nullptr, D_HID, D_HID, batch, sums);

    fc1_head<<<N_GRAPHS, 1024, 0, stream>>>(sums, batch, fc1_w, fc1_b, head_w, head_b, out);
}